// Round 13
// baseline (348.980 us; speedup 1.0000x reference)
//
#include <hip/hip_runtime.h>
#include <hip/hip_bf16.h>

// Problem: T=255, B=256, NIN=784, NOUT=40
// out layout: [spk_rec (255*256*40) | mem_rec (255*256*40)] fp32
#define T_STEPS 255
#define BATCH 256
#define NIN 784
#define NOUT 40
#define MROWS (T_STEPS * BATCH)          // 65280
#define TBN (T_STEPS * BATCH * NOUT)     // 2611200
#define BN_CH (BATCH * NOUT)             // 10240

#define BM 128        // rows per block -> grid 510
#define NCH 25        // K padded to 800 = 25 chunks of 32
#define WB_CHUNK 4608 // bf16 per chunk: 3 splits x 3 ntiles x 64 lanes x 8
#define EPS_NEAR 4e-4f

typedef short bf16x8 __attribute__((ext_vector_type(8)));
typedef float f32x4 __attribute__((ext_vector_type(4)));

__device__ __forceinline__ unsigned short f2bf(float f) {  // RNE
  unsigned u = __float_as_uint(f);
  u += 0x7fffu + ((u >> 16) & 1u);
  return (unsigned short)(u >> 16);
}
__device__ __forceinline__ float bf2f(unsigned short h) {
  return __uint_as_float(((unsigned)h) << 16);
}

__global__ void zero_ws(int* count, int* flag) { *count = 0; *flag = 0; }

// Pre-split W into fragment-major bf16: Wbg[c][s][t][lane][e] with
// k = c*32 + (lane>>4)*8 + e, n = t*16 + (lane&15); 3 splits via exact
// residuals (Sterbenz). 230 KB, L3-resident, built once per launch.
__global__ __launch_bounds__(256) void wsplit_kernel(
    const float* __restrict__ W, unsigned short* __restrict__ Wbg) {
  int i = blockIdx.x * 256 + threadIdx.x;
  if (i >= NCH * WB_CHUNK) return;
  int e = i & 7, l = (i >> 3) & 63, t = (i >> 9) % 3, s = (i / 1536) % 3,
      c = i / 4608;
  int k = c * 32 + (l >> 4) * 8 + e;
  int n = t * 16 + (l & 15);
  float v = (n < NOUT && k < NIN) ? W[n * NIN + k] : 0.f;
  unsigned short h1 = f2bf(v);
  float r1 = v - bf2f(h1);
  unsigned short h2 = f2bf(r1);
  float r2 = r1 - bf2f(h2);
  unsigned short h3 = f2bf(r2);
  Wbg[i] = (s == 0) ? h1 : (s == 1) ? h2 : h3;
}

// Split-precision bf16 MFMA GEMM. X tile in LDS with octet-safe XOR swizzle
// (slot ^= row&7 within each 8-slot row): staging octets (one row, 8 c4) and
// fragment octets (8 rows, fixed kgroup) both hit 8 distinct bank-groups.
// A-frags split to 3 bf16 levels in registers (exact residuals); 6 MFMA
// products accumulate small-terms-first into fp32. |cur err| <~1e-5 worst;
// decisions guarded by scan-flag + fp64 chainfix.
__global__ __launch_bounds__(256) void lif_gemm_mfma(
    const float* __restrict__ X, const unsigned short* __restrict__ Wbg,
    float* __restrict__ cur) {
  alignas(16) __shared__ float xs[4096];              // 1024 slots x 16B
  alignas(16) __shared__ unsigned short wb[WB_CHUNK]; // 9 KB
  const int tid = threadIdx.x;
  const int m0 = blockIdx.x * BM;
  const int w = tid >> 6, l = tid & 63;
  const int lr = l & 15, lg = l >> 4;

  f32x4 acc[2][3];
#pragma unroll
  for (int st = 0; st < 2; ++st)
#pragma unroll
    for (int t = 0; t < 3; ++t) acc[st][t] = (f32x4){0.f, 0.f, 0.f, 0.f};

  for (int c = 0; c < NCH; ++c) {
    const int k0 = c * 32;
    // stage X tile [128 rows][32 k] fp32, swizzled; zero-pad k>=784
#pragma unroll
    for (int i = 0; i < 4; ++i) {
      int S = tid + i * 256;            // swizzled slot id
      int row = S >> 3;
      int c4 = (S & 7) ^ (row & 7);     // unswizzled k-group
      int k = k0 + c4 * 4;
      float4 v = make_float4(0.f, 0.f, 0.f, 0.f);
      if (k < NIN)
        v = *reinterpret_cast<const float4*>(X + (size_t)(m0 + row) * NIN + k);
      *reinterpret_cast<float4*>(&xs[S * 4]) = v;
    }
    // stage W frags: 4608 bf16 = 576 x 16B, linear
#pragma unroll
    for (int i = 0; i < 3; ++i) {
      int id = tid + i * 256;
      if (id < 576)
        *reinterpret_cast<int4*>(&wb[id * 8]) = *reinterpret_cast<const int4*>(
            Wbg + (size_t)c * WB_CHUNK + (size_t)id * 8);
    }
    __syncthreads();

    bf16x8 B[3][3];
#pragma unroll
    for (int s = 0; s < 3; ++s)
#pragma unroll
      for (int t = 0; t < 3; ++t)
        B[s][t] = *reinterpret_cast<bf16x8*>(&wb[((s * 3 + t) * 64 + l) * 8]);

#pragma unroll
    for (int st = 0; st < 2; ++st) {
      int row = (w + st * 4) * 16 + lr;
      int sA = row * 8 + ((lg * 2) ^ (row & 7));
      int sB = row * 8 + ((lg * 2 + 1) ^ (row & 7));
      float4 fa = *reinterpret_cast<float4*>(&xs[sA * 4]);
      float4 fb = *reinterpret_cast<float4*>(&xs[sB * 4]);
      float f[8] = {fa.x, fa.y, fa.z, fa.w, fb.x, fb.y, fb.z, fb.w};
      union U { unsigned d[4]; bf16x8 v; } A1, A2, A3;
#pragma unroll
      for (int d = 0; d < 4; ++d) {
        float e0 = f[2 * d], e1 = f[2 * d + 1];
        unsigned short h0 = f2bf(e0), h1 = f2bf(e1);
        float r0 = e0 - bf2f(h0), r1 = e1 - bf2f(h1);
        unsigned short g0 = f2bf(r0), g1 = f2bf(r1);
        float s0 = r0 - bf2f(g0), s1 = r1 - bf2f(g1);
        A1.d[d] = (unsigned)h0 | ((unsigned)h1 << 16);
        A2.d[d] = (unsigned)g0 | ((unsigned)g1 << 16);
        A3.d[d] = (unsigned)f2bf(s0) | ((unsigned)f2bf(s1) << 16);
      }
#pragma unroll
      for (int t = 0; t < 3; ++t) {
        acc[st][t] = __builtin_amdgcn_mfma_f32_16x16x32_bf16(A3.v, B[0][t], acc[st][t], 0, 0, 0);
        acc[st][t] = __builtin_amdgcn_mfma_f32_16x16x32_bf16(A1.v, B[2][t], acc[st][t], 0, 0, 0);
        acc[st][t] = __builtin_amdgcn_mfma_f32_16x16x32_bf16(A2.v, B[1][t], acc[st][t], 0, 0, 0);
        acc[st][t] = __builtin_amdgcn_mfma_f32_16x16x32_bf16(A2.v, B[0][t], acc[st][t], 0, 0, 0);
        acc[st][t] = __builtin_amdgcn_mfma_f32_16x16x32_bf16(A1.v, B[1][t], acc[st][t], 0, 0, 0);
        acc[st][t] = __builtin_amdgcn_mfma_f32_16x16x32_bf16(A1.v, B[0][t], acc[st][t], 0, 0, 0);
      }
    }
    __syncthreads();
  }

  // D layout (m89-verified): col = lane&15, row = (lane>>4)*4 + reg
#pragma unroll
  for (int st = 0; st < 2; ++st)
#pragma unroll
    for (int t = 0; t < 3; ++t)
#pragma unroll
      for (int r = 0; r < 4; ++r) {
        int col = t * 16 + lr;
        if (col < NOUT) {
          size_t grow = (size_t)m0 + (w + st * 4) * 16 + lg * 4 + r;
          cur[grow * NOUT + col] = acc[st][t][r];
        }
      }
}

// 64 scattered fp64 sample dots vs cur: catches any MFMA-layout wrongness
// (errors O(1)); split-precision err <=~1e-4 passes tol 0.02.
__global__ __launch_bounds__(64) void check_kernel(
    const float* __restrict__ X, const float* __restrict__ W,
    const float* __restrict__ cur, int* __restrict__ flag) {
  const int l = threadIdx.x;
  const int r = (l * 1021) % MROWS;
  const int c = (l * 7 + 3) % NOUT;
  double dot = 0.0;
  for (int k = 0; k < NIN; k += 4) {
    float4 xv = *reinterpret_cast<const float4*>(X + (size_t)r * NIN + k);
    float4 wv = *reinterpret_cast<const float4*>(W + (size_t)c * NIN + k);
    dot = fma((double)xv.x, (double)wv.x, dot);
    dot = fma((double)xv.y, (double)wv.y, dot);
    dot = fma((double)xv.z, (double)wv.z, dot);
    dot = fma((double)xv.w, (double)wv.w, dot);
  }
  float got = cur[(size_t)r * NOUT + c];
  unsigned long long anybad = __ballot(fabs((double)got - dot) > 2e-2);
  if (l == 0) *flag = (anybad != 0ull) ? 1 : 0;
}

// Fallback: validated round-8 fp64-VALU GEMM, armed by flag.
__global__ __launch_bounds__(256) void lif_gemm_full(
    const float* __restrict__ X, const float* __restrict__ W,
    float* __restrict__ cur, const int* __restrict__ flag) {
  if (*(volatile const int*)flag == 0) return;
  __shared__ float xsf[128 * 60];
  __shared__ float wlf[NOUT * 60];
  const int tid = threadIdx.x;
  const int m0 = blockIdx.x * BM;
  const int w = tid >> 6, l = tid & 63;
  const int rl = l & 31, h = l >> 5;
  const int c0 = (w * 2 + h) * 5;
  double acc[4][5];
#pragma unroll
  for (int r = 0; r < 4; ++r)
#pragma unroll
    for (int c = 0; c < 5; ++c) acc[r][c] = 0.0;
  for (int k0 = 0; k0 < NIN; k0 += 56) {
#pragma unroll
    for (int i = 0; i < 7; ++i) {
      unsigned id = tid + i * 256u;
      unsigned row = id / 14u, c4 = id % 14u;
      float4 v = *reinterpret_cast<const float4*>(
          X + (size_t)(m0 + row) * NIN + k0 + c4 * 4);
      *reinterpret_cast<float4*>(&xsf[row * 60 + c4 * 4]) = v;
    }
#pragma unroll
    for (int i = 0; i < 3; ++i) {
      unsigned id = tid + i * 256u;
      if (id < NOUT * 14u) {
        unsigned row = id / 14u, c4 = id % 14u;
        float4 v = *reinterpret_cast<const float4*>(
            W + (size_t)row * NIN + k0 + c4 * 4);
        *reinterpret_cast<float4*>(&wlf[row * 60 + c4 * 4]) = v;
      }
    }
    __syncthreads();
#pragma unroll
    for (int kk = 0; kk < 56; kk += 4) {
      double xd[4][4];
#pragma unroll
      for (int r = 0; r < 4; ++r) {
        float4 xv = *reinterpret_cast<const float4*>(&xsf[(rl + 32 * r) * 60 + kk]);
        xd[r][0] = (double)xv.x; xd[r][1] = (double)xv.y;
        xd[r][2] = (double)xv.z; xd[r][3] = (double)xv.w;
      }
#pragma unroll
      for (int c = 0; c < 5; ++c) {
        float4 wv = *reinterpret_cast<const float4*>(&wlf[(c0 + c) * 60 + kk]);
        double wa = (double)wv.x, wb = (double)wv.y,
               wc = (double)wv.z, wd = (double)wv.w;
#pragma unroll
        for (int r = 0; r < 4; ++r) {
          acc[r][c] = fma(xd[r][0], wa, acc[r][c]);
          acc[r][c] = fma(xd[r][1], wb, acc[r][c]);
          acc[r][c] = fma(xd[r][2], wc, acc[r][c]);
          acc[r][c] = fma(xd[r][3], wd, acc[r][c]);
        }
      }
    }
    __syncthreads();
  }
#pragma unroll
  for (int r = 0; r < 4; ++r) {
    const size_t mrow = (size_t)m0 + rl + 32 * r;
#pragma unroll
    for (int c = 0; c < 5; ++c)
      cur[mrow * NOUT + c0 + c] = (float)acc[r][c];
  }
}

// Validated scan + near-boundary chain flagging: a chain is provably
// decision-correct unless some |mem-1| < EPS_NEAR (covers worst GEMM err
// x 1/(1-beta) amplification); flagged chains appended to worklist.
__global__ __launch_bounds__(64) void lif_scan_kernel(
    float* __restrict__ spk, float* __restrict__ curmem,
    int* __restrict__ count, int* __restrict__ wlist) {
  const int idx = blockIdx.x * 64 + threadIdx.x;
  float mem = 0.f;
  bool near = false;
  float c[15];
#pragma unroll
  for (int i = 0; i < 15; ++i) c[i] = curmem[(size_t)i * BN_CH + idx];
  for (int ch = 0; ch < 17; ++ch) {
    const int t0 = ch * 15;
    float n[15];
    if (ch != 16) {
#pragma unroll
      for (int i = 0; i < 15; ++i)
        n[i] = curmem[(size_t)(t0 + 15 + i) * BN_CH + idx];
    }
    float m_[15], s_[15];
#pragma unroll
    for (int i = 0; i < 15; ++i) {
      float reset = (mem > 1.0f) ? 1.0f : 0.0f;
      float decay = 0.95f * mem;
      asm volatile("" : "+v"(decay));  // forbid fma contraction
      float summ = decay + c[i];
      float mnew = summ * (1.0f - reset);
      near = near || (fabsf(mnew - 1.0f) < EPS_NEAR);
      m_[i] = mnew;
      s_[i] = (mnew > 1.0f) ? 1.0f : 0.0f;
      mem = mnew;
    }
#pragma unroll
    for (int i = 0; i < 15; ++i) {
      curmem[(size_t)(t0 + i) * BN_CH + idx] = m_[i];
      spk[(size_t)(t0 + i) * BN_CH + idx] = s_[i];
    }
    if (ch != 16) {
#pragma unroll
      for (int i = 0; i < 15; ++i) c[i] = n[i];
    }
  }
  if (near) {
    int p = atomicAdd(count, 1);
    wlist[p] = idx;
  }
}

// One wave per flagged chain: recompute cur in fp64 (lane-split dot +
// butterfly reduce), rerun the exact fp32 scan, overwrite spk/mem.
__global__ __launch_bounds__(256) void chainfix_kernel(
    const float* __restrict__ X, const float* __restrict__ W,
    float* __restrict__ spk, float* __restrict__ memout,
    const int* __restrict__ count, const int* __restrict__ wlist) {
  const int wv = blockIdx.x * 4 + (threadIdx.x >> 6);
  const int l = threadIdx.x & 63;
  if (wv >= *count) return;
  const int idx = wlist[wv];
  const int b = idx / NOUT, n = idx % NOUT;
  double wreg[13];
#pragma unroll
  for (int j = 0; j < 12; ++j) wreg[j] = (double)W[n * NIN + l + j * 64];
  wreg[12] = (l < 16) ? (double)W[n * NIN + 768 + l] : 0.0;
  float mem = 0.f;
  for (int t = 0; t < T_STEPS; ++t) {
    const float* xr = X + (size_t)(t * BATCH + b) * NIN;
    double s = 0.0;
#pragma unroll
    for (int j = 0; j < 12; ++j) s = fma((double)xr[l + j * 64], wreg[j], s);
    if (l < 16) s = fma((double)xr[768 + l], wreg[12], s);
#pragma unroll
    for (int off = 32; off; off >>= 1) s += __shfl_xor(s, off);
    float curf = (float)s;
    float reset = (mem > 1.0f) ? 1.0f : 0.0f;
    float decay = 0.95f * mem;
    asm volatile("" : "+v"(decay));
    float summ = decay + curf;
    float mnew = summ * (1.0f - reset);
    if (l == 0) {
      spk[(size_t)t * BN_CH + idx] = (mnew > 1.0f) ? 1.0f : 0.0f;
      memout[(size_t)t * BN_CH + idx] = mnew;
    }
    mem = mnew;
  }
}

extern "C" void kernel_launch(void* const* d_in, const int* in_sizes, int n_in,
                              void* d_out, int out_size, void* d_ws,
                              size_t ws_size, hipStream_t stream) {
  (void)in_sizes; (void)n_in; (void)out_size; (void)ws_size;
  const float* X = (const float*)d_in[0];
  const float* W = (const float*)d_in[1];
  float* out = (float*)d_out;
  float* spk = out;            // [255,256,40]
  float* memout = out + TBN;   // [255,256,40]: cur scratch then mem
  char* ws = (char*)d_ws;      // ws >= 42 MB (proven round 10)
  int* count = (int*)ws;
  int* flag = (int*)(ws + 4);
  int* wlist = (int*)(ws + 64);                       // 10240 ints
  unsigned short* Wbg = (unsigned short*)(ws + 41024); // 230400 B

  zero_ws<<<1, 1, 0, stream>>>(count, flag);
  wsplit_kernel<<<(NCH * WB_CHUNK + 255) / 256, 256, 0, stream>>>(W, Wbg);
  lif_gemm_mfma<<<MROWS / BM, 256, 0, stream>>>(X, Wbg, memout);
  check_kernel<<<1, 64, 0, stream>>>(X, W, memout, flag);
  lif_gemm_full<<<MROWS / BM, 256, 0, stream>>>(X, W, memout, flag);
  lif_scan_kernel<<<BN_CH / 64, 64, 0, stream>>>(spk, memout, count, wlist);
  chainfix_kernel<<<BN_CH / 4, 256, 0, stream>>>(X, W, spk, memout, count, wlist);
}

// Round 14
// 152.126 us; speedup vs baseline: 2.2940x; 2.2940x over previous
//
#include <hip/hip_runtime.h>
#include <hip/hip_bf16.h>

// Problem: T=255, B=256, NIN=784, NOUT=40
// out layout: [spk_rec (255*256*40) | mem_rec (255*256*40)] fp32
#define T_STEPS 255
#define BATCH 256
#define NIN 784
#define NOUT 40
#define MROWS (T_STEPS * BATCH)          // 65280
#define TBN (T_STEPS * BATCH * NOUT)     // 2611200
#define BN_CH (BATCH * NOUT)             // 10240

#define BM 128        // rows per block -> 510 tiles x 2 K-halves
#define NCH 25        // K padded to 800 = 25 chunks of 32
#define WB_CHUNK 4608 // bf16 per chunk: 3 splits x 3 ntiles x 64 lanes x 8
#define EPS_NEAR 4e-4f

typedef short bf16x8 __attribute__((ext_vector_type(8)));
typedef float f32x4 __attribute__((ext_vector_type(4)));

__device__ __forceinline__ unsigned short f2bf(float f) {  // RNE
  unsigned u = __float_as_uint(f);
  u += 0x7fffu + ((u >> 16) & 1u);
  return (unsigned short)(u >> 16);
}
__device__ __forceinline__ float bf2f(unsigned short h) {
  return __uint_as_float(((unsigned)h) << 16);
}

__global__ void zero_ws(int* count, int* flag) { *count = 0; *flag = 0; }

// Pre-split W into fragment-major bf16 (3 exact-residual levels). 230 KB.
__global__ __launch_bounds__(256) void wsplit_kernel(
    const float* __restrict__ W, unsigned short* __restrict__ Wbg) {
  int i = blockIdx.x * 256 + threadIdx.x;
  if (i >= NCH * WB_CHUNK) return;
  int e = i & 7, l = (i >> 3) & 63, t = (i >> 9) % 3, s = (i / 1536) % 3,
      c = i / 4608;
  int k = c * 32 + (l >> 4) * 8 + e;
  int n = t * 16 + (l & 15);
  float v = (n < NOUT && k < NIN) ? W[n * NIN + k] : 0.f;
  unsigned short h1 = f2bf(v);
  float r1 = v - bf2f(h1);
  unsigned short h2 = f2bf(r1);
  float r2 = r1 - bf2f(h2);
  unsigned short h3 = f2bf(r2);
  Wbg[i] = (s == 0) ? h1 : (s == 1) ? h2 : h3;
}

// Split-precision bf16 MFMA GEMM, split-K x2 (blockIdx.y = K-half).
// X tile LDS with octet-safe XOR swizzle (validated R13). Each half writes
// fp32 partials; combine adds. Decisions guarded by scan-flag + fp64 fix.
__global__ __launch_bounds__(256) void lif_gemm_mfma(
    const float* __restrict__ X, const unsigned short* __restrict__ Wbg,
    float* __restrict__ part) {
  alignas(16) __shared__ float xs[4096];              // 1024 slots x 16B
  alignas(16) __shared__ unsigned short wb[WB_CHUNK]; // 9 KB
  const int tid = threadIdx.x;
  const int m0 = blockIdx.x * BM;
  const int kh = blockIdx.y;
  const int c0c = kh * 13, c1c = (kh == 0) ? 13 : NCH;
  const int w = tid >> 6, l = tid & 63;
  const int lr = l & 15, lg = l >> 4;

  f32x4 acc[2][3];
#pragma unroll
  for (int st = 0; st < 2; ++st)
#pragma unroll
    for (int t = 0; t < 3; ++t) acc[st][t] = (f32x4){0.f, 0.f, 0.f, 0.f};

  for (int c = c0c; c < c1c; ++c) {
    const int k0 = c * 32;
#pragma unroll
    for (int i = 0; i < 4; ++i) {
      int S = tid + i * 256;            // swizzled slot id
      int row = S >> 3;
      int c4 = (S & 7) ^ (row & 7);     // unswizzled k-group
      int k = k0 + c4 * 4;
      float4 v = make_float4(0.f, 0.f, 0.f, 0.f);
      if (k < NIN)
        v = *reinterpret_cast<const float4*>(X + (size_t)(m0 + row) * NIN + k);
      *reinterpret_cast<float4*>(&xs[S * 4]) = v;
    }
#pragma unroll
    for (int i = 0; i < 3; ++i) {
      int id = tid + i * 256;
      if (id < 576)
        *reinterpret_cast<int4*>(&wb[id * 8]) = *reinterpret_cast<const int4*>(
            Wbg + (size_t)c * WB_CHUNK + (size_t)id * 8);
    }
    __syncthreads();

    bf16x8 B[3][3];
#pragma unroll
    for (int s = 0; s < 3; ++s)
#pragma unroll
      for (int t = 0; t < 3; ++t)
        B[s][t] = *reinterpret_cast<bf16x8*>(&wb[((s * 3 + t) * 64 + l) * 8]);

#pragma unroll
    for (int st = 0; st < 2; ++st) {
      int row = (w + st * 4) * 16 + lr;
      int sA = row * 8 + ((lg * 2) ^ (row & 7));
      int sB = row * 8 + ((lg * 2 + 1) ^ (row & 7));
      float4 fa = *reinterpret_cast<float4*>(&xs[sA * 4]);
      float4 fb = *reinterpret_cast<float4*>(&xs[sB * 4]);
      float f[8] = {fa.x, fa.y, fa.z, fa.w, fb.x, fb.y, fb.z, fb.w};
      union U { unsigned d[4]; bf16x8 v; } A1, A2, A3;
#pragma unroll
      for (int d = 0; d < 4; ++d) {
        float e0 = f[2 * d], e1 = f[2 * d + 1];
        unsigned short h0 = f2bf(e0), h1 = f2bf(e1);
        float r0 = e0 - bf2f(h0), r1 = e1 - bf2f(h1);
        unsigned short g0 = f2bf(r0), g1 = f2bf(r1);
        float s0 = r0 - bf2f(g0), s1 = r1 - bf2f(g1);
        A1.d[d] = (unsigned)h0 | ((unsigned)h1 << 16);
        A2.d[d] = (unsigned)g0 | ((unsigned)g1 << 16);
        A3.d[d] = (unsigned)f2bf(s0) | ((unsigned)f2bf(s1) << 16);
      }
#pragma unroll
      for (int t = 0; t < 3; ++t) {
        acc[st][t] = __builtin_amdgcn_mfma_f32_16x16x32_bf16(A3.v, B[0][t], acc[st][t], 0, 0, 0);
        acc[st][t] = __builtin_amdgcn_mfma_f32_16x16x32_bf16(A1.v, B[2][t], acc[st][t], 0, 0, 0);
        acc[st][t] = __builtin_amdgcn_mfma_f32_16x16x32_bf16(A2.v, B[1][t], acc[st][t], 0, 0, 0);
        acc[st][t] = __builtin_amdgcn_mfma_f32_16x16x32_bf16(A2.v, B[0][t], acc[st][t], 0, 0, 0);
        acc[st][t] = __builtin_amdgcn_mfma_f32_16x16x32_bf16(A1.v, B[1][t], acc[st][t], 0, 0, 0);
        acc[st][t] = __builtin_amdgcn_mfma_f32_16x16x32_bf16(A1.v, B[0][t], acc[st][t], 0, 0, 0);
      }
    }
    __syncthreads();
  }

  // D layout (m89-verified): col = lane&15, row = (lane>>4)*4 + reg
  float* p = part + (size_t)kh * TBN;
#pragma unroll
  for (int st = 0; st < 2; ++st)
#pragma unroll
    for (int t = 0; t < 3; ++t)
#pragma unroll
      for (int r = 0; r < 4; ++r) {
        int col = t * 16 + lr;
        if (col < NOUT) {
          size_t grow = (size_t)m0 + (w + st * 4) * 16 + lg * 4 + r;
          p[grow * NOUT + col] = acc[st][t][r];
        }
      }
}

__global__ __launch_bounds__(256) void combine_kernel(
    const float* __restrict__ part, float* __restrict__ cur) {
  size_t i = (size_t)blockIdx.x * 256 + threadIdx.x;
  if (i < TBN) cur[i] = part[i] + part[TBN + i];
}

// 64 scattered fp64 sample dots vs cur: catches gross GEMM wrongness.
__global__ __launch_bounds__(64) void check_kernel(
    const float* __restrict__ X, const float* __restrict__ W,
    const float* __restrict__ cur, int* __restrict__ flag) {
  const int l = threadIdx.x;
  const int r = (l * 1021) % MROWS;
  const int c = (l * 7 + 3) % NOUT;
  double dot = 0.0;
  for (int k = 0; k < NIN; k += 4) {
    float4 xv = *reinterpret_cast<const float4*>(X + (size_t)r * NIN + k);
    float4 wv = *reinterpret_cast<const float4*>(W + (size_t)c * NIN + k);
    dot = fma((double)xv.x, (double)wv.x, dot);
    dot = fma((double)xv.y, (double)wv.y, dot);
    dot = fma((double)xv.z, (double)wv.z, dot);
    dot = fma((double)xv.w, (double)wv.w, dot);
  }
  float got = cur[(size_t)r * NOUT + c];
  unsigned long long anybad = __ballot(fabs((double)got - dot) > 2e-2);
  if (l == 0) *flag = (anybad != 0ull) ? 1 : 0;
}

// Fallback: validated round-8 fp64-VALU GEMM, armed by flag.
__global__ __launch_bounds__(256) void lif_gemm_full(
    const float* __restrict__ X, const float* __restrict__ W,
    float* __restrict__ cur, const int* __restrict__ flag) {
  if (*(volatile const int*)flag == 0) return;
  __shared__ float xsf[128 * 60];
  __shared__ float wlf[NOUT * 60];
  const int tid = threadIdx.x;
  const int m0 = blockIdx.x * BM;
  const int w = tid >> 6, l = tid & 63;
  const int rl = l & 31, h = l >> 5;
  const int c0 = (w * 2 + h) * 5;
  double acc[4][5];
#pragma unroll
  for (int r = 0; r < 4; ++r)
#pragma unroll
    for (int c = 0; c < 5; ++c) acc[r][c] = 0.0;
  for (int k0 = 0; k0 < NIN; k0 += 56) {
#pragma unroll
    for (int i = 0; i < 7; ++i) {
      unsigned id = tid + i * 256u;
      unsigned row = id / 14u, c4 = id % 14u;
      float4 v = *reinterpret_cast<const float4*>(
          X + (size_t)(m0 + row) * NIN + k0 + c4 * 4);
      *reinterpret_cast<float4*>(&xsf[row * 60 + c4 * 4]) = v;
    }
#pragma unroll
    for (int i = 0; i < 3; ++i) {
      unsigned id = tid + i * 256u;
      if (id < NOUT * 14u) {
        unsigned row = id / 14u, c4 = id % 14u;
        float4 v = *reinterpret_cast<const float4*>(
            W + (size_t)row * NIN + k0 + c4 * 4);
        *reinterpret_cast<float4*>(&wlf[row * 60 + c4 * 4]) = v;
      }
    }
    __syncthreads();
#pragma unroll
    for (int kk = 0; kk < 56; kk += 4) {
      double xd[4][4];
#pragma unroll
      for (int r = 0; r < 4; ++r) {
        float4 xv = *reinterpret_cast<const float4*>(&xsf[(rl + 32 * r) * 60 + kk]);
        xd[r][0] = (double)xv.x; xd[r][1] = (double)xv.y;
        xd[r][2] = (double)xv.z; xd[r][3] = (double)xv.w;
      }
#pragma unroll
      for (int c = 0; c < 5; ++c) {
        float4 wv = *reinterpret_cast<const float4*>(&wlf[(c0 + c) * 60 + kk]);
        double wa = (double)wv.x, wb = (double)wv.y,
               wc = (double)wv.z, wd = (double)wv.w;
#pragma unroll
        for (int r = 0; r < 4; ++r) {
          acc[r][c] = fma(xd[r][0], wa, acc[r][c]);
          acc[r][c] = fma(xd[r][1], wb, acc[r][c]);
          acc[r][c] = fma(xd[r][2], wc, acc[r][c]);
          acc[r][c] = fma(xd[r][3], wd, acc[r][c]);
        }
      }
    }
    __syncthreads();
  }
#pragma unroll
  for (int r = 0; r < 4; ++r) {
    const size_t mrow = (size_t)m0 + rl + 32 * r;
#pragma unroll
    for (int c = 0; c < 5; ++c)
      cur[mrow * NOUT + c0 + c] = (float)acc[r][c];
  }
}

// Validated scan + near-boundary chain flagging (EPS covers worst GEMM err
// x 1/(1-beta) amplification with margin).
__global__ __launch_bounds__(64) void lif_scan_kernel(
    float* __restrict__ spk, float* __restrict__ curmem,
    int* __restrict__ count, int* __restrict__ wlist) {
  const int idx = blockIdx.x * 64 + threadIdx.x;
  float mem = 0.f;
  bool near = false;
  float c[15];
#pragma unroll
  for (int i = 0; i < 15; ++i) c[i] = curmem[(size_t)i * BN_CH + idx];
  for (int ch = 0; ch < 17; ++ch) {
    const int t0 = ch * 15;
    float n[15];
    if (ch != 16) {
#pragma unroll
      for (int i = 0; i < 15; ++i)
        n[i] = curmem[(size_t)(t0 + 15 + i) * BN_CH + idx];
    }
    float m_[15], s_[15];
#pragma unroll
    for (int i = 0; i < 15; ++i) {
      float reset = (mem > 1.0f) ? 1.0f : 0.0f;
      float decay = 0.95f * mem;
      asm volatile("" : "+v"(decay));  // forbid fma contraction
      float summ = decay + c[i];
      float mnew = summ * (1.0f - reset);
      near = near || (fabsf(mnew - 1.0f) < EPS_NEAR);
      m_[i] = mnew;
      s_[i] = (mnew > 1.0f) ? 1.0f : 0.0f;
      mem = mnew;
    }
#pragma unroll
    for (int i = 0; i < 15; ++i) {
      curmem[(size_t)(t0 + i) * BN_CH + idx] = m_[i];
      spk[(size_t)(t0 + i) * BN_CH + idx] = s_[i];
    }
    if (ch != 16) {
#pragma unroll
      for (int i = 0; i < 15; ++i) c[i] = n[i];
    }
  }
  if (near) {
    int p = atomicAdd(count, 1);
    wlist[p] = idx;
  }
}

// PARALLEL chain re-dot: one wave per (flagged chain, 8-t block), grid-
// strided. fp64 dot rounded to fp32 (the validated chainfix math) into
// curfix[f][t]. Replaces the serial 255-iteration latency chain of R13's
// chainfix (220us, 1.4% VALUBusy).
__global__ __launch_bounds__(256) void chaindot_kernel(
    const float* __restrict__ X, const float* __restrict__ W,
    const int* __restrict__ count, const int* __restrict__ wlist,
    float* __restrict__ curfix) {
  const int wv0 = blockIdx.x * 4 + (threadIdx.x >> 6);
  const int l = threadIdx.x & 63;
  const int njobs = *count * 32;
  for (int job = wv0; job < njobs; job += 10240) {
    const int f = job >> 5;
    const int tb = (job & 31) * 8;
    const int idx = wlist[f];
    const int b = idx / NOUT, n = idx % NOUT;
    double wreg[13];
#pragma unroll
    for (int j = 0; j < 12; ++j) wreg[j] = (double)W[n * NIN + l + j * 64];
    wreg[12] = (l < 16) ? (double)W[n * NIN + 768 + l] : 0.0;
#pragma unroll
    for (int u = 0; u < 8; ++u) {
      int t = tb + u;
      if (t >= T_STEPS) break;
      const float* xr = X + (size_t)(t * BATCH + b) * NIN;
      double s = 0.0;
#pragma unroll
      for (int j = 0; j < 12; ++j) s = fma((double)xr[l + j * 64], wreg[j], s);
      if (l < 16) s = fma((double)xr[768 + l], wreg[12], s);
#pragma unroll
      for (int off = 32; off; off >>= 1) s += __shfl_xor(s, off);
      if (l == 0) curfix[(size_t)f * T_STEPS + t] = (float)s;
    }
  }
}

// Serial scan replay for flagged chains from L2-resident curfix, with the
// validated 15-step prefetch. Overwrites spk/mem for those chains.
__global__ __launch_bounds__(64) void chainscan_kernel(
    float* __restrict__ spk, float* __restrict__ memout,
    const int* __restrict__ count, const int* __restrict__ wlist,
    const float* __restrict__ curfix) {
  const int f = blockIdx.x * 64 + threadIdx.x;
  if (f >= *count) return;
  const int idx = wlist[f];
  const float* cf = curfix + (size_t)f * T_STEPS;
  float mem = 0.f;
  float c[15];
#pragma unroll
  for (int i = 0; i < 15; ++i) c[i] = cf[i];
  for (int ch = 0; ch < 17; ++ch) {
    const int t0 = ch * 15;
    float nx[15];
    if (ch != 16) {
#pragma unroll
      for (int i = 0; i < 15; ++i) nx[i] = cf[t0 + 15 + i];
    }
#pragma unroll
    for (int i = 0; i < 15; ++i) {
      float reset = (mem > 1.0f) ? 1.0f : 0.0f;
      float decay = 0.95f * mem;
      asm volatile("" : "+v"(decay));
      float summ = decay + c[i];
      float mnew = summ * (1.0f - reset);
      spk[(size_t)(t0 + i) * BN_CH + idx] = (mnew > 1.0f) ? 1.0f : 0.0f;
      memout[(size_t)(t0 + i) * BN_CH + idx] = mnew;
      mem = mnew;
    }
    if (ch != 16) {
#pragma unroll
      for (int i = 0; i < 15; ++i) c[i] = nx[i];
    }
  }
}

extern "C" void kernel_launch(void* const* d_in, const int* in_sizes, int n_in,
                              void* d_out, int out_size, void* d_ws,
                              size_t ws_size, hipStream_t stream) {
  (void)in_sizes; (void)n_in; (void)out_size; (void)ws_size;
  const float* X = (const float*)d_in[0];
  const float* W = (const float*)d_in[1];
  float* out = (float*)d_out;
  float* spk = out;            // [255,256,40]
  float* memout = out + TBN;   // [255,256,40]: cur scratch then mem
  char* ws = (char*)d_ws;      // ws >= 41.8 MB (proven round 10); use 31.6 MB
  int* count = (int*)ws;
  int* flag = (int*)(ws + 4);
  int* wlist = (int*)(ws + 64);                        // 10240 ints
  unsigned short* Wbg = (unsigned short*)(ws + 41024); // 230400 B
  float* part = (float*)(ws + 271424);                 // 2 x TBN fp32
  float* curfix = (float*)(ws + 271424 + 2ull * TBN * 4);  // 10240x255 fp32

  zero_ws<<<1, 1, 0, stream>>>(count, flag);
  wsplit_kernel<<<(NCH * WB_CHUNK + 255) / 256, 256, 0, stream>>>(W, Wbg);
  dim3 ggrid(MROWS / BM, 2);
  lif_gemm_mfma<<<ggrid, 256, 0, stream>>>(X, Wbg, part);
  combine_kernel<<<(TBN + 255) / 256, 256, 0, stream>>>(part, memout);
  check_kernel<<<1, 64, 0, stream>>>(X, W, memout, flag);
  lif_gemm_full<<<MROWS / BM, 256, 0, stream>>>(X, W, memout, flag);
  lif_scan_kernel<<<BN_CH / 64, 64, 0, stream>>>(spk, memout, count, wlist);
  chaindot_kernel<<<2560, 256, 0, stream>>>(X, W, count, wlist, curfix);
  chainscan_kernel<<<BN_CH / 64, 64, 0, stream>>>(spk, memout, count, wlist,
                                                  curfix);
}

// Round 15
// 138.025 us; speedup vs baseline: 2.5284x; 1.1022x over previous
//
#include <hip/hip_runtime.h>
#include <hip/hip_bf16.h>

// Problem: T=255, B=256, NIN=784, NOUT=40
// out layout: [spk_rec (255*256*40) | mem_rec (255*256*40)] fp32
#define T_STEPS 255
#define BATCH 256
#define NIN 784
#define NOUT 40
#define MROWS (T_STEPS * BATCH)          // 65280
#define TBN (T_STEPS * BATCH * NOUT)     // 2611200
#define BN_CH (BATCH * NOUT)             // 10240

#define BM 128        // rows per block -> grid 510
#define NCH 25        // K padded to 800 = 25 chunks of 32
#define WB_CHUNK 4608 // bf16 per chunk: 3 splits x 3 ntiles x 64 lanes x 8
#define EPS_NEAR 4e-4f

typedef short bf16x8 __attribute__((ext_vector_type(8)));
typedef float f32x4 __attribute__((ext_vector_type(4)));

__device__ __forceinline__ unsigned short f2bf(float f) {  // RNE
  unsigned u = __float_as_uint(f);
  u += 0x7fffu + ((u >> 16) & 1u);
  return (unsigned short)(u >> 16);
}
__device__ __forceinline__ float bf2f(unsigned short h) {
  return __uint_as_float(((unsigned)h) << 16);
}

// Pre-split W into fragment-major bf16 (3 exact-residual levels). 230 KB.
// Thread 0 also zeroes the count/flag words (fused zero_ws).
__global__ __launch_bounds__(256) void wsplit_kernel(
    const float* __restrict__ W, unsigned short* __restrict__ Wbg,
    int* __restrict__ count, int* __restrict__ flag) {
  int i = blockIdx.x * 256 + threadIdx.x;
  if (i == 0) { *count = 0; *flag = 0; }
  if (i >= NCH * WB_CHUNK) return;
  int e = i & 7, l = (i >> 3) & 63, t = (i >> 9) % 3, s = (i / 1536) % 3,
      c = i / 4608;
  int k = c * 32 + (l >> 4) * 8 + e;
  int n = t * 16 + (l & 15);
  float v = (n < NOUT && k < NIN) ? W[n * NIN + k] : 0.f;
  unsigned short h1 = f2bf(v);
  float r1 = v - bf2f(h1);
  unsigned short h2 = f2bf(r1);
  float r2 = r1 - bf2f(h2);
  unsigned short h3 = f2bf(r2);
  Wbg[i] = (s == 0) ? h1 : (s == 1) ? h2 : h3;
}

// Split-precision bf16 MFMA GEMM, software-pipelined:
//  - B fragments load global->reg (Wbg is L2-resident; no LDS round-trip)
//  - next chunk's X tile + B frags are issued into registers BEFORE the
//    current chunk's split+MFMA compute; ds_write lands after the barrier.
// X tile LDS uses the octet-safe XOR swizzle (validated R13/R14).
// MFMA accumulation chain is bit-identical to the R13/R14-validated kernel;
// decisions are guarded by scan-flag + fp64 chainfix + 64-sample check.
__global__ __launch_bounds__(256) void lif_gemm_mfma(
    const float* __restrict__ X, const unsigned short* __restrict__ Wbg,
    float* __restrict__ cur) {
  alignas(16) __shared__ float xs[4096];  // 1024 slots x 16B (16 KB)
  const int tid = threadIdx.x;
  const int m0 = blockIdx.x * BM;
  const int w = tid >> 6, l = tid & 63;
  const int lr = l & 15, lg = l >> 4;

  // staging coords (fixed per thread): slot S = tid + i*256
  // row = S>>3, c4 = (S&7) ^ (row&7)
  f32x4 acc[2][3];
#pragma unroll
  for (int st = 0; st < 2; ++st)
#pragma unroll
    for (int t = 0; t < 3; ++t) acc[st][t] = (f32x4){0.f, 0.f, 0.f, 0.f};

  float4 gx[4];
  bf16x8 B[9], B2[9];

#define LOADX(C, DST)                                                     \
  do {                                                                    \
    const int k0_ = (C) * 32;                                             \
    _Pragma("unroll")                                                     \
    for (int i = 0; i < 4; ++i) {                                         \
      int S = tid + i * 256;                                              \
      int row = S >> 3;                                                   \
      int c4 = (S & 7) ^ (row & 7);                                       \
      int k = k0_ + c4 * 4;                                               \
      float4 v = make_float4(0.f, 0.f, 0.f, 0.f);                         \
      if (k < NIN)                                                        \
        v = *reinterpret_cast<const float4*>(X + (size_t)(m0 + row) * NIN + k); \
      DST[i] = v;                                                         \
    }                                                                     \
  } while (0)

#define LOADB(C, DST)                                                     \
  do {                                                                    \
    const unsigned short* base_ = Wbg + (size_t)(C) * WB_CHUNK;           \
    _Pragma("unroll")                                                     \
    for (int q = 0; q < 9; ++q)                                           \
      DST[q] = *reinterpret_cast<const bf16x8*>(base_ + (q * 64 + l) * 8); \
  } while (0)

#define WRITEX(SRC)                                                       \
  do {                                                                    \
    _Pragma("unroll")                                                     \
    for (int i = 0; i < 4; ++i) {                                         \
      int S = tid + i * 256;                                              \
      *reinterpret_cast<float4*>(&xs[S * 4]) = SRC[i];                    \
    }                                                                     \
  } while (0)

  LOADX(0, gx);
  LOADB(0, B);
  WRITEX(gx);
  __syncthreads();

  for (int c = 0; c < NCH; ++c) {
    const bool more = (c + 1 < NCH);
    if (more) {
      LOADX(c + 1, gx);   // issue early; compute below hides the latency
      LOADB(c + 1, B2);
    }

#pragma unroll
    for (int st = 0; st < 2; ++st) {
      int row = (w + st * 4) * 16 + lr;
      int sA = row * 8 + ((lg * 2) ^ (row & 7));
      int sB = row * 8 + ((lg * 2 + 1) ^ (row & 7));
      float4 fa = *reinterpret_cast<float4*>(&xs[sA * 4]);
      float4 fb = *reinterpret_cast<float4*>(&xs[sB * 4]);
      float f[8] = {fa.x, fa.y, fa.z, fa.w, fb.x, fb.y, fb.z, fb.w};
      union U { unsigned d[4]; bf16x8 v; } A1, A2, A3;
#pragma unroll
      for (int d = 0; d < 4; ++d) {
        float e0 = f[2 * d], e1 = f[2 * d + 1];
        unsigned short h0 = f2bf(e0), h1 = f2bf(e1);
        float r0 = e0 - bf2f(h0), r1 = e1 - bf2f(h1);
        unsigned short g0 = f2bf(r0), g1 = f2bf(r1);
        float s0 = r0 - bf2f(g0), s1 = r1 - bf2f(g1);
        A1.d[d] = (unsigned)h0 | ((unsigned)h1 << 16);
        A2.d[d] = (unsigned)g0 | ((unsigned)g1 << 16);
        A3.d[d] = (unsigned)f2bf(s0) | ((unsigned)f2bf(s1) << 16);
      }
#pragma unroll
      for (int t = 0; t < 3; ++t) {
        acc[st][t] = __builtin_amdgcn_mfma_f32_16x16x32_bf16(A3.v, B[0 * 3 + t], acc[st][t], 0, 0, 0);
        acc[st][t] = __builtin_amdgcn_mfma_f32_16x16x32_bf16(A1.v, B[2 * 3 + t], acc[st][t], 0, 0, 0);
        acc[st][t] = __builtin_amdgcn_mfma_f32_16x16x32_bf16(A2.v, B[1 * 3 + t], acc[st][t], 0, 0, 0);
        acc[st][t] = __builtin_amdgcn_mfma_f32_16x16x32_bf16(A2.v, B[0 * 3 + t], acc[st][t], 0, 0, 0);
        acc[st][t] = __builtin_amdgcn_mfma_f32_16x16x32_bf16(A1.v, B[1 * 3 + t], acc[st][t], 0, 0, 0);
        acc[st][t] = __builtin_amdgcn_mfma_f32_16x16x32_bf16(A1.v, B[0 * 3 + t], acc[st][t], 0, 0, 0);
      }
    }
    __syncthreads();        // all waves done reading xs
    if (more) {
      WRITEX(gx);           // waits vmcnt for gx only
      __syncthreads();
#pragma unroll
      for (int q = 0; q < 9; ++q) B[q] = B2[q];
    }
  }
#undef LOADX
#undef LOADB
#undef WRITEX

  // D layout (m89-verified): col = lane&15, row = (lane>>4)*4 + reg
#pragma unroll
  for (int st = 0; st < 2; ++st)
#pragma unroll
    for (int t = 0; t < 3; ++t)
#pragma unroll
      for (int r = 0; r < 4; ++r) {
        int col = t * 16 + lr;
        if (col < NOUT) {
          size_t grow = (size_t)m0 + (w + st * 4) * 16 + lg * 4 + r;
          cur[grow * NOUT + col] = acc[st][t][r];
        }
      }
}

// 64 scattered fp64 sample dots vs cur: catches gross GEMM wrongness.
__global__ __launch_bounds__(64) void check_kernel(
    const float* __restrict__ X, const float* __restrict__ W,
    const float* __restrict__ cur, int* __restrict__ flag) {
  const int l = threadIdx.x;
  const int r = (l * 1021) % MROWS;
  const int c = (l * 7 + 3) % NOUT;
  double dot = 0.0;
  for (int k = 0; k < NIN; k += 4) {
    float4 xv = *reinterpret_cast<const float4*>(X + (size_t)r * NIN + k);
    float4 wv = *reinterpret_cast<const float4*>(W + (size_t)c * NIN + k);
    dot = fma((double)xv.x, (double)wv.x, dot);
    dot = fma((double)xv.y, (double)wv.y, dot);
    dot = fma((double)xv.z, (double)wv.z, dot);
    dot = fma((double)xv.w, (double)wv.w, dot);
  }
  float got = cur[(size_t)r * NOUT + c];
  unsigned long long anybad = __ballot(fabs((double)got - dot) > 2e-2);
  if (l == 0) *flag = (anybad != 0ull) ? 1 : 0;
}

// Fallback: validated round-8 fp64-VALU GEMM, armed by flag.
__global__ __launch_bounds__(256) void lif_gemm_full(
    const float* __restrict__ X, const float* __restrict__ W,
    float* __restrict__ cur, const int* __restrict__ flag) {
  if (*(volatile const int*)flag == 0) return;
  __shared__ float xsf[128 * 60];
  __shared__ float wlf[NOUT * 60];
  const int tid = threadIdx.x;
  const int m0 = blockIdx.x * BM;
  const int w = tid >> 6, l = tid & 63;
  const int rl = l & 31, h = l >> 5;
  const int c0 = (w * 2 + h) * 5;
  double acc[4][5];
#pragma unroll
  for (int r = 0; r < 4; ++r)
#pragma unroll
    for (int c = 0; c < 5; ++c) acc[r][c] = 0.0;
  for (int k0 = 0; k0 < NIN; k0 += 56) {
#pragma unroll
    for (int i = 0; i < 7; ++i) {
      unsigned id = tid + i * 256u;
      unsigned row = id / 14u, c4 = id % 14u;
      float4 v = *reinterpret_cast<const float4*>(
          X + (size_t)(m0 + row) * NIN + k0 + c4 * 4);
      *reinterpret_cast<float4*>(&xsf[row * 60 + c4 * 4]) = v;
    }
#pragma unroll
    for (int i = 0; i < 3; ++i) {
      unsigned id = tid + i * 256u;
      if (id < NOUT * 14u) {
        unsigned row = id / 14u, c4 = id % 14u;
        float4 v = *reinterpret_cast<const float4*>(
            W + (size_t)row * NIN + k0 + c4 * 4);
        *reinterpret_cast<float4*>(&wlf[row * 60 + c4 * 4]) = v;
      }
    }
    __syncthreads();
#pragma unroll
    for (int kk = 0; kk < 56; kk += 4) {
      double xd[4][4];
#pragma unroll
      for (int r = 0; r < 4; ++r) {
        float4 xv = *reinterpret_cast<const float4*>(&xsf[(rl + 32 * r) * 60 + kk]);
        xd[r][0] = (double)xv.x; xd[r][1] = (double)xv.y;
        xd[r][2] = (double)xv.z; xd[r][3] = (double)xv.w;
      }
#pragma unroll
      for (int c = 0; c < 5; ++c) {
        float4 wv = *reinterpret_cast<const float4*>(&wlf[(c0 + c) * 60 + kk]);
        double wa = (double)wv.x, wb = (double)wv.y,
               wc = (double)wv.z, wd = (double)wv.w;
#pragma unroll
        for (int r = 0; r < 4; ++r) {
          acc[r][c] = fma(xd[r][0], wa, acc[r][c]);
          acc[r][c] = fma(xd[r][1], wb, acc[r][c]);
          acc[r][c] = fma(xd[r][2], wc, acc[r][c]);
          acc[r][c] = fma(xd[r][3], wd, acc[r][c]);
        }
      }
    }
    __syncthreads();
  }
#pragma unroll
  for (int r = 0; r < 4; ++r) {
    const size_t mrow = (size_t)m0 + rl + 32 * r;
#pragma unroll
    for (int c = 0; c < 5; ++c)
      cur[mrow * NOUT + c0 + c] = (float)acc[r][c];
  }
}

// Validated scan + near-boundary chain flagging (EPS covers worst GEMM err
// x 1/(1-beta) amplification with margin).
__global__ __launch_bounds__(64) void lif_scan_kernel(
    float* __restrict__ spk, float* __restrict__ curmem,
    int* __restrict__ count, int* __restrict__ wlist) {
  const int idx = blockIdx.x * 64 + threadIdx.x;
  float mem = 0.f;
  bool near = false;
  float c[15];
#pragma unroll
  for (int i = 0; i < 15; ++i) c[i] = curmem[(size_t)i * BN_CH + idx];
  for (int ch = 0; ch < 17; ++ch) {
    const int t0 = ch * 15;
    float n[15];
    if (ch != 16) {
#pragma unroll
      for (int i = 0; i < 15; ++i)
        n[i] = curmem[(size_t)(t0 + 15 + i) * BN_CH + idx];
    }
    float m_[15], s_[15];
#pragma unroll
    for (int i = 0; i < 15; ++i) {
      float reset = (mem > 1.0f) ? 1.0f : 0.0f;
      float decay = 0.95f * mem;
      asm volatile("" : "+v"(decay));  // forbid fma contraction
      float summ = decay + c[i];
      float mnew = summ * (1.0f - reset);
      near = near || (fabsf(mnew - 1.0f) < EPS_NEAR);
      m_[i] = mnew;
      s_[i] = (mnew > 1.0f) ? 1.0f : 0.0f;
      mem = mnew;
    }
#pragma unroll
    for (int i = 0; i < 15; ++i) {
      curmem[(size_t)(t0 + i) * BN_CH + idx] = m_[i];
      spk[(size_t)(t0 + i) * BN_CH + idx] = s_[i];
    }
    if (ch != 16) {
#pragma unroll
      for (int i = 0; i < 15; ++i) c[i] = n[i];
    }
  }
  if (near) {
    int p = atomicAdd(count, 1);
    wlist[p] = idx;
  }
}

// PARALLEL chain re-dot: one wave per (flagged chain, 8-t block), grid-
// strided; fp64 dot rounded to fp32 into curfix.
__global__ __launch_bounds__(256) void chaindot_kernel(
    const float* __restrict__ X, const float* __restrict__ W,
    const int* __restrict__ count, const int* __restrict__ wlist,
    float* __restrict__ curfix) {
  const int wv0 = blockIdx.x * 4 + (threadIdx.x >> 6);
  const int l = threadIdx.x & 63;
  const int njobs = *count * 32;
  for (int job = wv0; job < njobs; job += 10240) {
    const int f = job >> 5;
    const int tb = (job & 31) * 8;
    const int idx = wlist[f];
    const int b = idx / NOUT, n = idx % NOUT;
    double wreg[13];
#pragma unroll
    for (int j = 0; j < 12; ++j) wreg[j] = (double)W[n * NIN + l + j * 64];
    wreg[12] = (l < 16) ? (double)W[n * NIN + 768 + l] : 0.0;
#pragma unroll
    for (int u = 0; u < 8; ++u) {
      int t = tb + u;
      if (t >= T_STEPS) break;
      const float* xr = X + (size_t)(t * BATCH + b) * NIN;
      double s = 0.0;
#pragma unroll
      for (int j = 0; j < 12; ++j) s = fma((double)xr[l + j * 64], wreg[j], s);
      if (l < 16) s = fma((double)xr[768 + l], wreg[12], s);
#pragma unroll
      for (int off = 32; off; off >>= 1) s += __shfl_xor(s, off);
      if (l == 0) curfix[(size_t)f * T_STEPS + t] = (float)s;
    }
  }
}

// Serial scan replay for flagged chains from curfix; overwrites spk/mem.
__global__ __launch_bounds__(64) void chainscan_kernel(
    float* __restrict__ spk, float* __restrict__ memout,
    const int* __restrict__ count, const int* __restrict__ wlist,
    const float* __restrict__ curfix) {
  const int f = blockIdx.x * 64 + threadIdx.x;
  if (f >= *count) return;
  const int idx = wlist[f];
  const float* cf = curfix + (size_t)f * T_STEPS;
  float mem = 0.f;
  float c[15];
#pragma unroll
  for (int i = 0; i < 15; ++i) c[i] = cf[i];
  for (int ch = 0; ch < 17; ++ch) {
    const int t0 = ch * 15;
    float nx[15];
    if (ch != 16) {
#pragma unroll
      for (int i = 0; i < 15; ++i) nx[i] = cf[t0 + 15 + i];
    }
#pragma unroll
    for (int i = 0; i < 15; ++i) {
      float reset = (mem > 1.0f) ? 1.0f : 0.0f;
      float decay = 0.95f * mem;
      asm volatile("" : "+v"(decay));
      float summ = decay + c[i];
      float mnew = summ * (1.0f - reset);
      spk[(size_t)(t0 + i) * BN_CH + idx] = (mnew > 1.0f) ? 1.0f : 0.0f;
      memout[(size_t)(t0 + i) * BN_CH + idx] = mnew;
      mem = mnew;
    }
    if (ch != 16) {
#pragma unroll
      for (int i = 0; i < 15; ++i) c[i] = nx[i];
    }
  }
}

extern "C" void kernel_launch(void* const* d_in, const int* in_sizes, int n_in,
                              void* d_out, int out_size, void* d_ws,
                              size_t ws_size, hipStream_t stream) {
  (void)in_sizes; (void)n_in; (void)out_size; (void)ws_size;
  const float* X = (const float*)d_in[0];
  const float* W = (const float*)d_in[1];
  float* out = (float*)d_out;
  float* spk = out;            // [255,256,40]
  float* memout = out + TBN;   // [255,256,40]: cur scratch then mem
  char* ws = (char*)d_ws;      // ~10.7 MB used (ws proven >= 41.8 MB)
  int* count = (int*)ws;
  int* flag = (int*)(ws + 4);
  int* wlist = (int*)(ws + 64);                        // 10240 ints
  unsigned short* Wbg = (unsigned short*)(ws + 41024); // 230400 B
  float* curfix = (float*)(ws + 271424);               // 10240x255 fp32

  wsplit_kernel<<<(NCH * WB_CHUNK + 255) / 256, 256, 0, stream>>>(W, Wbg,
                                                                  count, flag);
  lif_gemm_mfma<<<MROWS / BM, 256, 0, stream>>>(X, Wbg, memout);
  check_kernel<<<1, 64, 0, stream>>>(X, W, memout, flag);
  lif_gemm_full<<<MROWS / BM, 256, 0, stream>>>(X, W, memout, flag);
  lif_scan_kernel<<<BN_CH / 64, 64, 0, stream>>>(spk, memout, count, wlist);
  chaindot_kernel<<<2560, 256, 0, stream>>>(X, W, count, wlist, curfix);
  chainscan_kernel<<<BN_CH / 64, 64, 0, stream>>>(spk, memout, count, wlist,
                                                  curfix);
}

// Round 16
// 107.310 us; speedup vs baseline: 3.2521x; 1.2862x over previous
//
#include <hip/hip_runtime.h>
#include <hip/hip_bf16.h>

// Problem: T=255, B=256, NIN=784, NOUT=40
// out layout: [spk_rec (255*256*40) | mem_rec (255*256*40)] fp32
#define T_STEPS 255
#define BATCH 256
#define NIN 784
#define NOUT 40
#define MROWS (T_STEPS * BATCH)          // 65280
#define TBN (T_STEPS * BATCH * NOUT)     // 2611200
#define BN_CH (BATCH * NOUT)             // 10240

#define BM 128        // rows per block -> grid 510
#define NCH 25        // K padded to 800 = 25 chunks of 32
#define WB_CHUNK 4608 // bf16 per chunk: 3 splits x 3 ntiles x 64 lanes x 8
#define EPS_NEAR 2e-4f
#define SCH 30        // scan chunk length (9 hops instead of 17)

typedef short bf16x8 __attribute__((ext_vector_type(8)));
typedef float f32x4 __attribute__((ext_vector_type(4)));

__device__ __forceinline__ unsigned short f2bf(float f) {  // RNE
  unsigned u = __float_as_uint(f);
  u += 0x7fffu + ((u >> 16) & 1u);
  return (unsigned short)(u >> 16);
}
__device__ __forceinline__ float bf2f(unsigned short h) {
  return __uint_as_float(((unsigned)h) << 16);
}

// Pre-split W into fragment-major bf16 (3 exact-residual levels). 230 KB.
// Thread 0 also zeroes the flag-count word.
__global__ __launch_bounds__(256) void wsplit_kernel(
    const float* __restrict__ W, unsigned short* __restrict__ Wbg,
    int* __restrict__ count) {
  int i = blockIdx.x * 256 + threadIdx.x;
  if (i == 0) *count = 0;
  if (i >= NCH * WB_CHUNK) return;
  int e = i & 7, l = (i >> 3) & 63, t = (i >> 9) % 3, s = (i / 1536) % 3,
      c = i / 4608;
  int k = c * 32 + (l >> 4) * 8 + e;
  int n = t * 16 + (l & 15);
  float v = (n < NOUT && k < NIN) ? W[n * NIN + k] : 0.f;
  unsigned short h1 = f2bf(v);
  float r1 = v - bf2f(h1);
  unsigned short h2 = f2bf(r1);
  float r2 = r1 - bf2f(h2);
  unsigned short h3 = f2bf(r2);
  Wbg[i] = (s == 0) ? h1 : (s == 1) ? h2 : h3;
}

// Split-precision bf16 MFMA GEMM, software-pipelined (validated R13-R15):
//  - B fragments global->reg (Wbg L2-resident; no LDS round-trip)
//  - next chunk's X tile + B frags issued into registers before compute;
//    ds_write lands after the post-compute barrier.
// X tile LDS uses the octet-safe XOR swizzle. Decisions guarded by
// scan-flag + fp64 chainfix.
__global__ __launch_bounds__(256) void lif_gemm_mfma(
    const float* __restrict__ X, const unsigned short* __restrict__ Wbg,
    float* __restrict__ cur) {
  alignas(16) __shared__ float xs[4096];  // 1024 slots x 16B (16 KB)
  const int tid = threadIdx.x;
  const int m0 = blockIdx.x * BM;
  const int w = tid >> 6, l = tid & 63;
  const int lr = l & 15, lg = l >> 4;

  f32x4 acc[2][3];
#pragma unroll
  for (int st = 0; st < 2; ++st)
#pragma unroll
    for (int t = 0; t < 3; ++t) acc[st][t] = (f32x4){0.f, 0.f, 0.f, 0.f};

  float4 gx[4];
  bf16x8 B[9], B2[9];

#define LOADX(C, DST)                                                     \
  do {                                                                    \
    const int k0_ = (C) * 32;                                             \
    _Pragma("unroll")                                                     \
    for (int i = 0; i < 4; ++i) {                                         \
      int S = tid + i * 256;                                              \
      int row = S >> 3;                                                   \
      int c4 = (S & 7) ^ (row & 7);                                       \
      int k = k0_ + c4 * 4;                                               \
      float4 v = make_float4(0.f, 0.f, 0.f, 0.f);                         \
      if (k < NIN)                                                        \
        v = *reinterpret_cast<const float4*>(X + (size_t)(m0 + row) * NIN + k); \
      DST[i] = v;                                                         \
    }                                                                     \
  } while (0)

#define LOADB(C, DST)                                                     \
  do {                                                                    \
    const unsigned short* base_ = Wbg + (size_t)(C) * WB_CHUNK;           \
    _Pragma("unroll")                                                     \
    for (int q = 0; q < 9; ++q)                                           \
      DST[q] = *reinterpret_cast<const bf16x8*>(base_ + (q * 64 + l) * 8); \
  } while (0)

#define WRITEX(SRC)                                                       \
  do {                                                                    \
    _Pragma("unroll")                                                     \
    for (int i = 0; i < 4; ++i) {                                         \
      int S = tid + i * 256;                                              \
      *reinterpret_cast<float4*>(&xs[S * 4]) = SRC[i];                    \
    }                                                                     \
  } while (0)

  LOADX(0, gx);
  LOADB(0, B);
  WRITEX(gx);
  __syncthreads();

  for (int c = 0; c < NCH; ++c) {
    const bool more = (c + 1 < NCH);
    if (more) {
      LOADX(c + 1, gx);   // issue early; compute below hides the latency
      LOADB(c + 1, B2);
    }

#pragma unroll
    for (int st = 0; st < 2; ++st) {
      int row = (w + st * 4) * 16 + lr;
      int sA = row * 8 + ((lg * 2) ^ (row & 7));
      int sB = row * 8 + ((lg * 2 + 1) ^ (row & 7));
      float4 fa = *reinterpret_cast<float4*>(&xs[sA * 4]);
      float4 fb = *reinterpret_cast<float4*>(&xs[sB * 4]);
      float f[8] = {fa.x, fa.y, fa.z, fa.w, fb.x, fb.y, fb.z, fb.w};
      union U { unsigned d[4]; bf16x8 v; } A1, A2, A3;
#pragma unroll
      for (int d = 0; d < 4; ++d) {
        float e0 = f[2 * d], e1 = f[2 * d + 1];
        unsigned short h0 = f2bf(e0), h1 = f2bf(e1);
        float r0 = e0 - bf2f(h0), r1 = e1 - bf2f(h1);
        unsigned short g0 = f2bf(r0), g1 = f2bf(r1);
        float s0 = r0 - bf2f(g0), s1 = r1 - bf2f(g1);
        A1.d[d] = (unsigned)h0 | ((unsigned)h1 << 16);
        A2.d[d] = (unsigned)g0 | ((unsigned)g1 << 16);
        A3.d[d] = (unsigned)f2bf(s0) | ((unsigned)f2bf(s1) << 16);
      }
#pragma unroll
      for (int t = 0; t < 3; ++t) {
        acc[st][t] = __builtin_amdgcn_mfma_f32_16x16x32_bf16(A3.v, B[0 * 3 + t], acc[st][t], 0, 0, 0);
        acc[st][t] = __builtin_amdgcn_mfma_f32_16x16x32_bf16(A1.v, B[2 * 3 + t], acc[st][t], 0, 0, 0);
        acc[st][t] = __builtin_amdgcn_mfma_f32_16x16x32_bf16(A2.v, B[1 * 3 + t], acc[st][t], 0, 0, 0);
        acc[st][t] = __builtin_amdgcn_mfma_f32_16x16x32_bf16(A2.v, B[0 * 3 + t], acc[st][t], 0, 0, 0);
        acc[st][t] = __builtin_amdgcn_mfma_f32_16x16x32_bf16(A1.v, B[1 * 3 + t], acc[st][t], 0, 0, 0);
        acc[st][t] = __builtin_amdgcn_mfma_f32_16x16x32_bf16(A1.v, B[0 * 3 + t], acc[st][t], 0, 0, 0);
      }
    }
    __syncthreads();        // all waves done reading xs
    if (more) {
      WRITEX(gx);           // waits vmcnt for gx only
      __syncthreads();
#pragma unroll
      for (int q = 0; q < 9; ++q) B[q] = B2[q];
    }
  }
#undef LOADX
#undef LOADB
#undef WRITEX

  // D layout (m89-verified): col = lane&15, row = (lane>>4)*4 + reg
#pragma unroll
  for (int st = 0; st < 2; ++st)
#pragma unroll
    for (int t = 0; t < 3; ++t)
#pragma unroll
      for (int r = 0; r < 4; ++r) {
        int col = t * 16 + lr;
        if (col < NOUT) {
          size_t grow = (size_t)m0 + (w + st * 4) * 16 + lg * 4 + r;
          cur[grow * NOUT + col] = acc[st][t][r];
        }
      }
}

// Validated scan math + near-boundary chain flagging; 30-step chunks with
// next-chunk prefetch (9 L2 latency hops instead of 17).
__global__ __launch_bounds__(64) void lif_scan_kernel(
    float* __restrict__ spk, float* __restrict__ curmem,
    int* __restrict__ count, int* __restrict__ wlist) {
  const int idx = blockIdx.x * 64 + threadIdx.x;
  float mem = 0.f;
  bool near = false;
  float c[SCH];
#pragma unroll
  for (int i = 0; i < SCH; ++i) c[i] = curmem[(size_t)i * BN_CH + idx];
  for (int ch = 0; ch < 9; ++ch) {
    const int t0 = ch * SCH;
    float nx[SCH];
    if (ch != 8) {
#pragma unroll
      for (int i = 0; i < SCH; ++i) {
        int t = t0 + SCH + i;
        nx[i] = (t < T_STEPS) ? curmem[(size_t)t * BN_CH + idx] : 0.f;
      }
    }
#pragma unroll
    for (int i = 0; i < SCH; ++i) {
      if (t0 + i < T_STEPS) {
        float reset = (mem > 1.0f) ? 1.0f : 0.0f;
        float decay = 0.95f * mem;
        asm volatile("" : "+v"(decay));  // forbid fma contraction
        float summ = decay + c[i];
        float mnew = summ * (1.0f - reset);
        near = near || (fabsf(mnew - 1.0f) < EPS_NEAR);
        curmem[(size_t)(t0 + i) * BN_CH + idx] = mnew;
        spk[(size_t)(t0 + i) * BN_CH + idx] = (mnew > 1.0f) ? 1.0f : 0.0f;
        mem = mnew;
      }
    }
    if (ch != 8) {
#pragma unroll
      for (int i = 0; i < SCH; ++i) c[i] = nx[i];
    }
  }
  if (near) {
    int p = atomicAdd(count, 1);
    wlist[p] = idx;
  }
}

// PARALLEL chain re-dot: one wave per (flagged chain, 8-t block), grid-
// strided; fp64 dot rounded to fp32 into curfix (validated R14/R15).
__global__ __launch_bounds__(256) void chaindot_kernel(
    const float* __restrict__ X, const float* __restrict__ W,
    const int* __restrict__ count, const int* __restrict__ wlist,
    float* __restrict__ curfix) {
  const int wv0 = blockIdx.x * 4 + (threadIdx.x >> 6);
  const int l = threadIdx.x & 63;
  const int njobs = *count * 32;
  for (int job = wv0; job < njobs; job += 10240) {
    const int f = job >> 5;
    const int tb = (job & 31) * 8;
    const int idx = wlist[f];
    const int b = idx / NOUT, n = idx % NOUT;
    double wreg[13];
#pragma unroll
    for (int j = 0; j < 12; ++j) wreg[j] = (double)W[n * NIN + l + j * 64];
    wreg[12] = (l < 16) ? (double)W[n * NIN + 768 + l] : 0.0;
#pragma unroll
    for (int u = 0; u < 8; ++u) {
      int t = tb + u;
      if (t >= T_STEPS) break;
      const float* xr = X + (size_t)(t * BATCH + b) * NIN;
      double s = 0.0;
#pragma unroll
      for (int j = 0; j < 12; ++j) s = fma((double)xr[l + j * 64], wreg[j], s);
      if (l < 16) s = fma((double)xr[768 + l], wreg[12], s);
#pragma unroll
      for (int off = 32; off; off >>= 1) s += __shfl_xor(s, off);
      if (l == 0) curfix[(size_t)f * T_STEPS + t] = (float)s;
    }
  }
}

// Serial scan replay for flagged chains from curfix; overwrites spk/mem.
__global__ __launch_bounds__(64) void chainscan_kernel(
    float* __restrict__ spk, float* __restrict__ memout,
    const int* __restrict__ count, const int* __restrict__ wlist,
    const float* __restrict__ curfix) {
  const int f = blockIdx.x * 64 + threadIdx.x;
  if (f >= *count) return;
  const int idx = wlist[f];
  const float* cf = curfix + (size_t)f * T_STEPS;
  float mem = 0.f;
  float c[15];
#pragma unroll
  for (int i = 0; i < 15; ++i) c[i] = cf[i];
  for (int ch = 0; ch < 17; ++ch) {
    const int t0 = ch * 15;
    float nx[15];
    if (ch != 16) {
#pragma unroll
      for (int i = 0; i < 15; ++i) nx[i] = cf[t0 + 15 + i];
    }
#pragma unroll
    for (int i = 0; i < 15; ++i) {
      float reset = (mem > 1.0f) ? 1.0f : 0.0f;
      float decay = 0.95f * mem;
      asm volatile("" : "+v"(decay));
      float summ = decay + c[i];
      float mnew = summ * (1.0f - reset);
      spk[(size_t)(t0 + i) * BN_CH + idx] = (mnew > 1.0f) ? 1.0f : 0.0f;
      memout[(size_t)(t0 + i) * BN_CH + idx] = mnew;
      mem = mnew;
    }
    if (ch != 16) {
#pragma unroll
      for (int i = 0; i < 15; ++i) c[i] = nx[i];
    }
  }
}

extern "C" void kernel_launch(void* const* d_in, const int* in_sizes, int n_in,
                              void* d_out, int out_size, void* d_ws,
                              size_t ws_size, hipStream_t stream) {
  (void)in_sizes; (void)n_in; (void)out_size; (void)ws_size;
  const float* X = (const float*)d_in[0];
  const float* W = (const float*)d_in[1];
  float* out = (float*)d_out;
  float* spk = out;            // [255,256,40]
  float* memout = out + TBN;   // [255,256,40]: cur scratch then mem
  char* ws = (char*)d_ws;      // ~10.7 MB used (ws proven >= 41.8 MB)
  int* count = (int*)ws;
  int* wlist = (int*)(ws + 64);                        // 10240 ints
  unsigned short* Wbg = (unsigned short*)(ws + 41024); // 230400 B
  float* curfix = (float*)(ws + 271424);               // 10240x255 fp32

  wsplit_kernel<<<(NCH * WB_CHUNK + 255) / 256, 256, 0, stream>>>(W, Wbg,
                                                                  count);
  lif_gemm_mfma<<<MROWS / BM, 256, 0, stream>>>(X, Wbg, memout);
  lif_scan_kernel<<<BN_CH / 64, 64, 0, stream>>>(spk, memout, count, wlist);
  chaindot_kernel<<<2560, 256, 0, stream>>>(X, W, count, wlist, curfix);
  chainscan_kernel<<<BN_CH / 64, 64, 0, stream>>>(spk, memout, count, wlist,
                                                  curfix);
}

// Round 17
// 107.060 us; speedup vs baseline: 3.2597x; 1.0023x over previous
//
#include <hip/hip_runtime.h>
#include <hip/hip_bf16.h>

// Problem: T=255, B=256, NIN=784, NOUT=40
// out layout: [spk_rec (255*256*40) | mem_rec (255*256*40)] fp32
#define T_STEPS 255
#define BATCH 256
#define NIN 784
#define NOUT 40
#define MROWS (T_STEPS * BATCH)          // 65280
#define TBN (T_STEPS * BATCH * NOUT)     // 2611200
#define BN_CH (BATCH * NOUT)             // 10240

#define BM 128        // rows per block -> grid 510
#define NCH 25        // K padded to 800 = 25 chunks of 32
#define WB_CHUNK 4608 // bf16 per chunk: 3 splits x 3 ntiles x 64 lanes x 8
#define EPS_NEAR 2e-4f
#define SCH 30        // scan chunk length (9 hops)

typedef short bf16x8 __attribute__((ext_vector_type(8)));
typedef float f32x4 __attribute__((ext_vector_type(4)));

__device__ __forceinline__ unsigned short f2bf(float f) {  // RNE
  unsigned u = __float_as_uint(f);
  u += 0x7fffu + ((u >> 16) & 1u);
  return (unsigned short)(u >> 16);
}
__device__ __forceinline__ float bf2f(unsigned short h) {
  return __uint_as_float(((unsigned)h) << 16);
}

// Pre-split W into fragment-major bf16 (3 exact-residual levels). 230 KB.
__global__ __launch_bounds__(256) void wsplit_kernel(
    const float* __restrict__ W, unsigned short* __restrict__ Wbg,
    int* __restrict__ count) {
  int i = blockIdx.x * 256 + threadIdx.x;
  if (i == 0) *count = 0;
  if (i >= NCH * WB_CHUNK) return;
  int e = i & 7, l = (i >> 3) & 63, t = (i >> 9) % 3, s = (i / 1536) % 3,
      c = i / 4608;
  int k = c * 32 + (l >> 4) * 8 + e;
  int n = t * 16 + (l & 15);
  float v = (n < NOUT && k < NIN) ? W[n * NIN + k] : 0.f;
  unsigned short h1 = f2bf(v);
  float r1 = v - bf2f(h1);
  unsigned short h2 = f2bf(r1);
  float r2 = r1 - bf2f(h2);
  unsigned short h3 = f2bf(r2);
  Wbg[i] = (s == 0) ? h1 : (s == 1) ? h2 : h3;
}

// Split-precision bf16 MFMA GEMM (accumulation chain bit-identical to the
// R13-R16-validated kernel), now with LDS double-buffer + 2-deep register
// prefetch: at chunk c we ds_write chunk c+1 from registers loaded at chunk
// c-1 (landed -> zero vm-stall), issue X loads for c+2, compute c, ONE
// barrier. Loop unrolled x2 so all register sets are statically indexed.
__global__ __launch_bounds__(256) void lif_gemm_mfma(
    const float* __restrict__ X, const unsigned short* __restrict__ Wbg,
    float* __restrict__ cur) {
  alignas(16) __shared__ float xs0[4096];  // buf for even chunks
  alignas(16) __shared__ float xs1[4096];  // buf for odd chunks
  const int tid = threadIdx.x;
  const int m0 = blockIdx.x * BM;
  const int w = tid >> 6, l = tid & 63;
  const int lr = l & 15, lg = l >> 4;

  f32x4 acc[2][3];
#pragma unroll
  for (int st = 0; st < 2; ++st)
#pragma unroll
    for (int t = 0; t < 3; ++t) acc[st][t] = (f32x4){0.f, 0.f, 0.f, 0.f};

  float4 gxA[4], gxB[4];
  bf16x8 BA[9], BB[9];

#define LOADX(C, DST)                                                     \
  do {                                                                    \
    const int k0_ = (C) * 32;                                             \
    _Pragma("unroll")                                                     \
    for (int i = 0; i < 4; ++i) {                                         \
      int S = tid + i * 256;                                              \
      int row = S >> 3;                                                   \
      int c4 = (S & 7) ^ (row & 7);                                       \
      int k = k0_ + c4 * 4;                                               \
      float4 v = make_float4(0.f, 0.f, 0.f, 0.f);                         \
      if (k < NIN)                                                        \
        v = *reinterpret_cast<const float4*>(X + (size_t)(m0 + row) * NIN + k); \
      DST[i] = v;                                                         \
    }                                                                     \
  } while (0)

#define LOADB(C, DST)                                                     \
  do {                                                                    \
    const unsigned short* base_ = Wbg + (size_t)(C) * WB_CHUNK;           \
    _Pragma("unroll")                                                     \
    for (int q = 0; q < 9; ++q)                                           \
      DST[q] = *reinterpret_cast<const bf16x8*>(base_ + (q * 64 + l) * 8); \
  } while (0)

#define WRITEX(BUF, SRC)                                                  \
  do {                                                                    \
    _Pragma("unroll")                                                     \
    for (int i = 0; i < 4; ++i) {                                         \
      int S = tid + i * 256;                                              \
      *reinterpret_cast<float4*>(&(BUF)[S * 4]) = SRC[i];                 \
    }                                                                     \
  } while (0)

#define COMPUTE(BUF, BSET)                                                \
  do {                                                                    \
    _Pragma("unroll")                                                     \
    for (int st = 0; st < 2; ++st) {                                      \
      int row = (w + st * 4) * 16 + lr;                                   \
      int sA = row * 8 + ((lg * 2) ^ (row & 7));                          \
      int sB = row * 8 + ((lg * 2 + 1) ^ (row & 7));                      \
      float4 fa = *reinterpret_cast<float4*>(&(BUF)[sA * 4]);             \
      float4 fb = *reinterpret_cast<float4*>(&(BUF)[sB * 4]);             \
      float f[8] = {fa.x, fa.y, fa.z, fa.w, fb.x, fb.y, fb.z, fb.w};      \
      union U { unsigned d[4]; bf16x8 v; } A1, A2, A3;                    \
      _Pragma("unroll")                                                   \
      for (int d = 0; d < 4; ++d) {                                       \
        float e0 = f[2 * d], e1 = f[2 * d + 1];                           \
        unsigned short h0 = f2bf(e0), h1 = f2bf(e1);                      \
        float r0 = e0 - bf2f(h0), r1 = e1 - bf2f(h1);                     \
        unsigned short g0 = f2bf(r0), g1 = f2bf(r1);                      \
        float s0 = r0 - bf2f(g0), s1 = r1 - bf2f(g1);                     \
        A1.d[d] = (unsigned)h0 | ((unsigned)h1 << 16);                    \
        A2.d[d] = (unsigned)g0 | ((unsigned)g1 << 16);                    \
        A3.d[d] = (unsigned)f2bf(s0) | ((unsigned)f2bf(s1) << 16);        \
      }                                                                   \
      _Pragma("unroll")                                                   \
      for (int t = 0; t < 3; ++t) {                                       \
        acc[st][t] = __builtin_amdgcn_mfma_f32_16x16x32_bf16(A3.v, BSET[0 * 3 + t], acc[st][t], 0, 0, 0); \
        acc[st][t] = __builtin_amdgcn_mfma_f32_16x16x32_bf16(A1.v, BSET[2 * 3 + t], acc[st][t], 0, 0, 0); \
        acc[st][t] = __builtin_amdgcn_mfma_f32_16x16x32_bf16(A2.v, BSET[1 * 3 + t], acc[st][t], 0, 0, 0); \
        acc[st][t] = __builtin_amdgcn_mfma_f32_16x16x32_bf16(A2.v, BSET[0 * 3 + t], acc[st][t], 0, 0, 0); \
        acc[st][t] = __builtin_amdgcn_mfma_f32_16x16x32_bf16(A1.v, BSET[1 * 3 + t], acc[st][t], 0, 0, 0); \
        acc[st][t] = __builtin_amdgcn_mfma_f32_16x16x32_bf16(A1.v, BSET[0 * 3 + t], acc[st][t], 0, 0, 0); \
      }                                                                   \
    }                                                                     \
  } while (0)

  // prologue: chunk0 -> buf0 (vm-wait here only), chunk1 -> regs
  LOADX(0, gxA);
  LOADB(0, BA);
  WRITEX(xs0, gxA);
  LOADX(1, gxB);
  LOADB(1, BB);
  __syncthreads();

  // chunks 0..23 in pairs; chunk 24 in epilogue
  for (int c = 0; c < 24; c += 2) {
    // even chunk c: buf0/BA; write chunk c+1 (gxB, landed); issue c+2
    WRITEX(xs1, gxB);
    if (c + 2 < NCH) LOADX(c + 2, gxA);
    COMPUTE(xs0, BA);
    if (c + 2 < NCH) LOADB(c + 2, BA);
    __syncthreads();
    // odd chunk c+1: buf1/BB; write chunk c+2 (gxA, landed); issue c+3
    if (c + 2 < NCH) WRITEX(xs0, gxA);
    if (c + 3 < NCH) LOADX(c + 3, gxB);
    COMPUTE(xs1, BB);
    if (c + 3 < NCH) LOADB(c + 3, BB);
    __syncthreads();
  }
  COMPUTE(xs0, BA);  // chunk 24
#undef LOADX
#undef LOADB
#undef WRITEX
#undef COMPUTE

  // D layout (m89-verified): col = lane&15, row = (lane>>4)*4 + reg
#pragma unroll
  for (int st = 0; st < 2; ++st)
#pragma unroll
    for (int t = 0; t < 3; ++t)
#pragma unroll
      for (int r = 0; r < 4; ++r) {
        int col = t * 16 + lr;
        if (col < NOUT) {
          size_t grow = (size_t)m0 + (w + st * 4) * 16 + lg * 4 + r;
          cur[grow * NOUT + col] = acc[st][t][r];
        }
      }
}

// Validated scan math + near-boundary chain flagging; 30-step chunks with
// next-chunk prefetch (9 L2 latency hops).
__global__ __launch_bounds__(64) void lif_scan_kernel(
    float* __restrict__ spk, float* __restrict__ curmem,
    int* __restrict__ count, int* __restrict__ wlist) {
  const int idx = blockIdx.x * 64 + threadIdx.x;
  float mem = 0.f;
  bool near = false;
  float c[SCH];
#pragma unroll
  for (int i = 0; i < SCH; ++i) c[i] = curmem[(size_t)i * BN_CH + idx];
  for (int ch = 0; ch < 9; ++ch) {
    const int t0 = ch * SCH;
    float nx[SCH];
    if (ch != 8) {
#pragma unroll
      for (int i = 0; i < SCH; ++i) {
        int t = t0 + SCH + i;
        nx[i] = (t < T_STEPS) ? curmem[(size_t)t * BN_CH + idx] : 0.f;
      }
    }
#pragma unroll
    for (int i = 0; i < SCH; ++i) {
      if (t0 + i < T_STEPS) {
        float reset = (mem > 1.0f) ? 1.0f : 0.0f;
        float decay = 0.95f * mem;
        asm volatile("" : "+v"(decay));  // forbid fma contraction
        float summ = decay + c[i];
        float mnew = summ * (1.0f - reset);
        near = near || (fabsf(mnew - 1.0f) < EPS_NEAR);
        curmem[(size_t)(t0 + i) * BN_CH + idx] = mnew;
        spk[(size_t)(t0 + i) * BN_CH + idx] = (mnew > 1.0f) ? 1.0f : 0.0f;
        mem = mnew;
      }
    }
    if (ch != 8) {
#pragma unroll
      for (int i = 0; i < SCH; ++i) c[i] = nx[i];
    }
  }
  if (near) {
    int p = atomicAdd(count, 1);
    wlist[p] = idx;
  }
}

// PARALLEL chain re-dot: one wave per (flagged chain, 8-t block), grid-
// strided; fp64 dot rounded to fp32 into curfix (validated R14-R16).
__global__ __launch_bounds__(256) void chaindot_kernel(
    const float* __restrict__ X, const float* __restrict__ W,
    const int* __restrict__ count, const int* __restrict__ wlist,
    float* __restrict__ curfix) {
  const int wv0 = blockIdx.x * 4 + (threadIdx.x >> 6);
  const int l = threadIdx.x & 63;
  const int njobs = *count * 32;
  for (int job = wv0; job < njobs; job += 10240) {
    const int f = job >> 5;
    const int tb = (job & 31) * 8;
    const int idx = wlist[f];
    const int b = idx / NOUT, n = idx % NOUT;
    double wreg[13];
#pragma unroll
    for (int j = 0; j < 12; ++j) wreg[j] = (double)W[n * NIN + l + j * 64];
    wreg[12] = (l < 16) ? (double)W[n * NIN + 768 + l] : 0.0;
#pragma unroll
    for (int u = 0; u < 8; ++u) {
      int t = tb + u;
      if (t >= T_STEPS) break;
      const float* xr = X + (size_t)(t * BATCH + b) * NIN;
      double s = 0.0;
#pragma unroll
      for (int j = 0; j < 12; ++j) s = fma((double)xr[l + j * 64], wreg[j], s);
      if (l < 16) s = fma((double)xr[768 + l], wreg[12], s);
#pragma unroll
      for (int off = 32; off; off >>= 1) s += __shfl_xor(s, off);
      if (l == 0) curfix[(size_t)f * T_STEPS + t] = (float)s;
    }
  }
}

// Serial scan replay for flagged chains from curfix; overwrites spk/mem.
__global__ __launch_bounds__(64) void chainscan_kernel(
    float* __restrict__ spk, float* __restrict__ memout,
    const int* __restrict__ count, const int* __restrict__ wlist,
    const float* __restrict__ curfix) {
  const int f = blockIdx.x * 64 + threadIdx.x;
  if (f >= *count) return;
  const int idx = wlist[f];
  const float* cf = curfix + (size_t)f * T_STEPS;
  float mem = 0.f;
  float c[15];
#pragma unroll
  for (int i = 0; i < 15; ++i) c[i] = cf[i];
  for (int ch = 0; ch < 17; ++ch) {
    const int t0 = ch * 15;
    float nx[15];
    if (ch != 16) {
#pragma unroll
      for (int i = 0; i < 15; ++i) nx[i] = cf[t0 + 15 + i];
    }
#pragma unroll
    for (int i = 0; i < 15; ++i) {
      float reset = (mem > 1.0f) ? 1.0f : 0.0f;
      float decay = 0.95f * mem;
      asm volatile("" : "+v"(decay));
      float summ = decay + c[i];
      float mnew = summ * (1.0f - reset);
      spk[(size_t)(t0 + i) * BN_CH + idx] = (mnew > 1.0f) ? 1.0f : 0.0f;
      memout[(size_t)(t0 + i) * BN_CH + idx] = mnew;
      mem = mnew;
    }
    if (ch != 16) {
#pragma unroll
      for (int i = 0; i < 15; ++i) c[i] = nx[i];
    }
  }
}

extern "C" void kernel_launch(void* const* d_in, const int* in_sizes, int n_in,
                              void* d_out, int out_size, void* d_ws,
                              size_t ws_size, hipStream_t stream) {
  (void)in_sizes; (void)n_in; (void)out_size; (void)ws_size;
  const float* X = (const float*)d_in[0];
  const float* W = (const float*)d_in[1];
  float* out = (float*)d_out;
  float* spk = out;            // [255,256,40]
  float* memout = out + TBN;   // [255,256,40]: cur scratch then mem
  char* ws = (char*)d_ws;      // ~10.7 MB used (ws proven >= 41.8 MB)
  int* count = (int*)ws;
  int* wlist = (int*)(ws + 64);                        // 10240 ints
  unsigned short* Wbg = (unsigned short*)(ws + 41024); // 230400 B
  float* curfix = (float*)(ws + 271424);               // 10240x255 fp32

  wsplit_kernel<<<(NCH * WB_CHUNK + 255) / 256, 256, 0, stream>>>(W, Wbg,
                                                                  count);
  lif_gemm_mfma<<<MROWS / BM, 256, 0, stream>>>(X, Wbg, memout);
  lif_scan_kernel<<<BN_CH / 64, 64, 0, stream>>>(spk, memout, count, wlist);
  chaindot_kernel<<<2560, 256, 0, stream>>>(X, W, count, wlist, curfix);
  chainscan_kernel<<<BN_CH / 64, 64, 0, stream>>>(spk, memout, count, wlist,
                                                  curfix);
}